// Round 1
// baseline (85.830 us; speedup 1.0000x reference)
//
#include <hip/hip_runtime.h>
#include <math.h>

#define N_POINTS 32768
#define NUM_EMBED 8192
#define CHUNKS 16
#define CAND_PER_CHUNK (NUM_EMBED / CHUNKS)   // 512
#define CSTRIDE 4096                           // 64*64, channel stride in z [B,C,H,W]

// ---------------- kernel A: ee[j] = sum(e_j^2), replicating XLA mul + sequential adds
__global__ void vq_ee_kernel(const float4* __restrict__ E, float* __restrict__ ee) {
    int j = blockIdx.x * blockDim.x + threadIdx.x;
    if (j < NUM_EMBED) {
        float4 e = E[j];
        float s = __fmul_rn(e.x, e.x);
        s = __fadd_rn(s, __fmul_rn(e.y, e.y));
        s = __fadd_rn(s, __fmul_rn(e.z, e.z));
        s = __fadd_rn(s, __fmul_rn(e.w, e.w));
        ee[j] = s;
    }
}

// ---------------- kernel B: per (point, chunk) partial argmin
__global__ __launch_bounds__(256) void vq_partial_kernel(
        const float* __restrict__ z, const float4* __restrict__ E,
        const float* __restrict__ ee,
        float* __restrict__ wd, int* __restrict__ wi) {
    int n = blockIdx.x * 256 + threadIdx.x;     // point id, lanes consecutive -> coalesced z
    int c = blockIdx.y;                          // candidate chunk
    int b = n >> 12;
    int hw = n & 4095;
    const float* zp = z + b * 16384 + hw;
    float z0 = zp[0];
    float z1 = zp[CSTRIDE];
    float z2 = zp[2 * CSTRIDE];
    float z3 = zp[3 * CSTRIDE];
    // zz: mul + sequential adds (no contraction)
    float zz = __fmul_rn(z0, z0);
    zz = __fadd_rn(zz, __fmul_rn(z1, z1));
    zz = __fadd_rn(zz, __fmul_rn(z2, z2));
    zz = __fadd_rn(zz, __fmul_rn(z3, z3));

    float bestd = __builtin_inff();
    int besti = 0;
    const int j0 = c * CAND_PER_CHUNK;
    #pragma unroll 8
    for (int t = 0; t < CAND_PER_CHUNK; ++t) {
        int j = j0 + t;                          // wave-uniform -> scalar loads
        float4 e = E[j];
        float eej = ee[j];
        // Eigen gebp: ascending-k fma chain, acc starts at z0*e0 (== fma(z0,e0,0))
        float dot = __fmul_rn(z0, e.x);
        dot = __fmaf_rn(z1, e.y, dot);
        dot = __fmaf_rn(z2, e.z, dot);
        dot = __fmaf_rn(z3, e.w, dot);
        // d = (zz + ee) - 2*dot ; the *2 is exact so one fma reproduces the fsub rounding
        float d = __fmaf_rn(-2.0f, dot, __fadd_rn(zz, eej));
        if (d < bestd) { bestd = d; besti = j; } // strict < keeps first index (tie-break)
    }
    wd[c * N_POINTS + n] = bestd;
    wi[c * N_POINTS + n] = besti;
}

// ---------------- kernel C: combine chunks, write z_q_ste (NCHW), idx-as-float, loss partials
__global__ __launch_bounds__(256) void vq_finalize_kernel(
        const float* __restrict__ z, const float4* __restrict__ E,
        const float* __restrict__ wd, const int* __restrict__ wi,
        float* __restrict__ out, double* __restrict__ partial) {
    __shared__ double sdata[256];
    int n = blockIdx.x * 256 + threadIdx.x;
    float bestd = __builtin_inff();
    int besti = 0;
    #pragma unroll
    for (int c = 0; c < CHUNKS; ++c) {           // ascending chunk + strict < -> global first-min
        float d = wd[c * N_POINTS + n];
        int i = wi[c * N_POINTS + n];
        if (d < bestd) { bestd = d; besti = i; }
    }
    int b = n >> 12;
    int hw = n & 4095;
    const float* zp = z + b * 16384 + hw;
    float* op = out + b * 16384 + hw;
    float4 e = E[besti];
    float ec[4] = {e.x, e.y, e.z, e.w};
    double ds = 0.0;
    #pragma unroll
    for (int cc = 0; cc < 4; ++cc) {
        float zc = zp[cc * CSTRIDE];
        float t = __fsub_rn(ec[cc], zc);         // z_q - z (the sg'd diff, also loss diff)
        float q = __fadd_rn(zc, t);              // straight-through: z + (z_q - z)
        op[cc * CSTRIDE] = q;
        float t2 = __fmul_rn(t, t);
        ds += (double)t2;
    }
    out[131073 + n] = (float)besti;              // indices as float32 (exact)

    sdata[threadIdx.x] = ds;
    __syncthreads();
    #pragma unroll
    for (int s = 128; s > 0; s >>= 1) {
        if (threadIdx.x < s) sdata[threadIdx.x] += sdata[threadIdx.x + s];
        __syncthreads();
    }
    if (threadIdx.x == 0) partial[blockIdx.x] = sdata[0];
}

// ---------------- kernel D: deterministic loss reduce
__global__ void vq_loss_kernel(const double* __restrict__ partial, float* __restrict__ out) {
    __shared__ double sdata[128];
    int t = threadIdx.x;
    sdata[t] = partial[t];
    __syncthreads();
    #pragma unroll
    for (int s = 64; s > 0; s >>= 1) {
        if (t < s) sdata[t] += sdata[t + s];
        __syncthreads();
    }
    if (t == 0) {
        float m = (float)(sdata[0] / 131072.0);
        // loss = mean + BETA*mean (both means are numerically identical)
        out[131072] = __fadd_rn(m, __fmul_rn(0.25f, m));
    }
}

extern "C" void kernel_launch(void* const* d_in, const int* in_sizes, int n_in,
                              void* d_out, int out_size, void* d_ws, size_t ws_size,
                              hipStream_t stream) {
    const float* z = (const float*)d_in[0];
    const float4* E = (const float4*)d_in[1];
    float* out = (float*)d_out;

    char* ws = (char*)d_ws;
    float* ee = (float*)ws;                                  // 8192 f32 = 32 KB
    float* wd = (float*)(ws + 32768);                        // 16*32768 f32 = 2 MB
    int*   wi = (int*)(ws + 32768 + (size_t)CHUNKS * N_POINTS * 4);  // 2 MB
    double* partial = (double*)(ws + 32768 + (size_t)CHUNKS * N_POINTS * 8); // 128 doubles

    vq_ee_kernel<<<NUM_EMBED / 256, 256, 0, stream>>>(E, ee);
    vq_partial_kernel<<<dim3(N_POINTS / 256, CHUNKS), 256, 0, stream>>>(z, E, ee, wd, wi);
    vq_finalize_kernel<<<N_POINTS / 256, 256, 0, stream>>>(z, E, wd, wi, out, partial);
    vq_loss_kernel<<<1, 128, 0, stream>>>(partial, out);
}

// Round 2
// 72.211 us; speedup vs baseline: 1.1886x; 1.1886x over previous
//
#include <hip/hip_runtime.h>
#include <math.h>

typedef float v2f __attribute__((ext_vector_type(2)));

#define N_POINTS 32768
#define NUM_EMBED 8192
#define NPAIRS 4096
#define CHUNKS 16
#define PAIRS_PER_CHUNK (NPAIRS / CHUNKS)   // 256 pairs = 512 candidates per chunk
#define CSTRIDE 4096                         // 64*64, channel stride in z [B,C,H,W]

// ---------------- kernel A: build pair-interleaved codebook + ee (exact XLA arithmetic)
__global__ void vq_prep_kernel(const float4* __restrict__ E,
                               v2f* __restrict__ Epk, v2f* __restrict__ eev) {
    int p = blockIdx.x * 256 + threadIdx.x;
    if (p < NPAIRS) {
        float4 a = E[2 * p];
        float4 b = E[2 * p + 1];
        Epk[4 * p + 0] = (v2f){a.x, b.x};
        Epk[4 * p + 1] = (v2f){a.y, b.y};
        Epk[4 * p + 2] = (v2f){a.z, b.z};
        Epk[4 * p + 3] = (v2f){a.w, b.w};
        float ea = __fmul_rn(a.x, a.x);
        ea = __fadd_rn(ea, __fmul_rn(a.y, a.y));
        ea = __fadd_rn(ea, __fmul_rn(a.z, a.z));
        ea = __fadd_rn(ea, __fmul_rn(a.w, a.w));
        float eb = __fmul_rn(b.x, b.x);
        eb = __fadd_rn(eb, __fmul_rn(b.y, b.y));
        eb = __fadd_rn(eb, __fmul_rn(b.z, b.z));
        eb = __fadd_rn(eb, __fmul_rn(b.w, b.w));
        eev[p] = (v2f){ea, eb};
    }
}

// ---------------- kernel B: per (point, chunk) partial argmin, 2 candidates/iter via packed f32
__global__ __launch_bounds__(256) void vq_partial_kernel(
        const float* __restrict__ z, const v2f* __restrict__ Epk,
        const v2f* __restrict__ eev,
        float* __restrict__ wd, int* __restrict__ wi) {
    int n = blockIdx.x * 256 + threadIdx.x;     // point id, lanes consecutive -> coalesced z
    int c = blockIdx.y;                          // candidate chunk
    int b = n >> 12;
    int hw = n & 4095;
    const float* zp = z + b * 16384 + hw;
    float z0 = zp[0];
    float z1 = zp[CSTRIDE];
    float z2 = zp[2 * CSTRIDE];
    float z3 = zp[3 * CSTRIDE];
    // zz: mul + sequential adds (no contraction) — matches reference
    float zz = __fmul_rn(z0, z0);
    zz = __fadd_rn(zz, __fmul_rn(z1, z1));
    zz = __fadd_rn(zz, __fmul_rn(z2, z2));
    zz = __fadd_rn(zz, __fmul_rn(z3, z3));

    // hoisted broadcast pairs
    v2f z0v = {z0, z0}, z1v = {z1, z1}, z2v = {z2, z2}, z3v = {z3, z3};
    v2f zzv = {zz, zz};
    v2f m2v = {-2.0f, -2.0f};

    float bdl = __builtin_inff(), bdh = __builtin_inff();
    int bpl = 0, bph = 0;
    const int p0 = c * PAIRS_PER_CHUNK;
    #pragma unroll 4
    for (int t = 0; t < PAIRS_PER_CHUNK; ++t) {
        int p = p0 + t;                          // wave-uniform -> scalar loads
        v2f e0 = Epk[4 * p + 0];
        v2f e1 = Epk[4 * p + 1];
        v2f e2 = Epk[4 * p + 2];
        v2f e3 = Epk[4 * p + 3];
        v2f ee2 = eev[p];
        // per-half arithmetic identical to the scalar reference chain:
        v2f szz = zzv + ee2;                                 // zz + ee_j   (rn)
        v2f dot = z0v * e0;                                  // z0*e0       (rn)
        dot = __builtin_elementwise_fma(z1v, e1, dot);       // fma chain ascending k
        dot = __builtin_elementwise_fma(z2v, e2, dot);
        dot = __builtin_elementwise_fma(z3v, e3, dot);
        v2f d2 = __builtin_elementwise_fma(m2v, dot, szz);   // (zz+ee) - 2*dot
        if (d2.x < bdl) { bdl = d2.x; bpl = p; }             // strict < : first index wins
        if (d2.y < bdh) { bdh = d2.y; bph = p; }
    }
    // resolve halves with global first-index tie-break
    int il = 2 * bpl, ih = 2 * bph + 1;
    float bestd; int besti;
    if (bdh < bdl) { bestd = bdh; besti = ih; }
    else           { bestd = bdl; besti = (bdl == bdh && ih < il) ? ih : il; }
    wd[c * N_POINTS + n] = bestd;
    wi[c * N_POINTS + n] = besti;
}

// ---------------- kernel C: combine chunks, write z_q_ste (NCHW), idx-as-float, loss partials
__global__ __launch_bounds__(256) void vq_finalize_kernel(
        const float* __restrict__ z, const float4* __restrict__ E,
        const float* __restrict__ wd, const int* __restrict__ wi,
        float* __restrict__ out, double* __restrict__ partial) {
    __shared__ double sdata[256];
    int n = blockIdx.x * 256 + threadIdx.x;
    float bestd = __builtin_inff();
    int besti = 0;
    #pragma unroll
    for (int c = 0; c < CHUNKS; ++c) {           // ascending chunk + strict < -> global first-min
        float d = wd[c * N_POINTS + n];
        int i = wi[c * N_POINTS + n];
        if (d < bestd) { bestd = d; besti = i; }
    }
    int b = n >> 12;
    int hw = n & 4095;
    const float* zp = z + b * 16384 + hw;
    float* op = out + b * 16384 + hw;
    float4 e = E[besti];
    float ec[4] = {e.x, e.y, e.z, e.w};
    double ds = 0.0;
    #pragma unroll
    for (int cc = 0; cc < 4; ++cc) {
        float zc = zp[cc * CSTRIDE];
        float t = __fsub_rn(ec[cc], zc);         // z_q - z (the sg'd diff, also loss diff)
        float q = __fadd_rn(zc, t);              // straight-through: z + (z_q - z)
        op[cc * CSTRIDE] = q;
        float t2 = __fmul_rn(t, t);
        ds += (double)t2;
    }
    out[131073 + n] = (float)besti;              // indices as float32 (exact)

    sdata[threadIdx.x] = ds;
    __syncthreads();
    #pragma unroll
    for (int s = 128; s > 0; s >>= 1) {
        if (threadIdx.x < s) sdata[threadIdx.x] += sdata[threadIdx.x + s];
        __syncthreads();
    }
    if (threadIdx.x == 0) partial[blockIdx.x] = sdata[0];
}

// ---------------- kernel D: deterministic loss reduce
__global__ void vq_loss_kernel(const double* __restrict__ partial, float* __restrict__ out) {
    __shared__ double sdata[128];
    int t = threadIdx.x;
    sdata[t] = partial[t];
    __syncthreads();
    #pragma unroll
    for (int s = 64; s > 0; s >>= 1) {
        if (t < s) sdata[t] += sdata[t + s];
        __syncthreads();
    }
    if (t == 0) {
        float m = (float)(sdata[0] / 131072.0);
        // loss = mean + BETA*mean (both means are numerically identical)
        out[131072] = __fadd_rn(m, __fmul_rn(0.25f, m));
    }
}

extern "C" void kernel_launch(void* const* d_in, const int* in_sizes, int n_in,
                              void* d_out, int out_size, void* d_ws, size_t ws_size,
                              hipStream_t stream) {
    const float* z = (const float*)d_in[0];
    const float4* E = (const float4*)d_in[1];
    float* out = (float*)d_out;

    char* ws = (char*)d_ws;
    v2f* Epk = (v2f*)ws;                                     // 4096*4 v2f = 128 KB
    v2f* eev = (v2f*)(ws + 131072);                          // 4096 v2f = 32 KB
    float* wd = (float*)(ws + 131072 + 32768);               // 16*32768 f32 = 2 MB
    int*   wi = (int*)(ws + 131072 + 32768 + (size_t)CHUNKS * N_POINTS * 4); // 2 MB
    double* partial = (double*)(ws + 131072 + 32768 + (size_t)CHUNKS * N_POINTS * 8); // 1 KB

    vq_prep_kernel<<<NPAIRS / 256, 256, 0, stream>>>(E, Epk, eev);
    vq_partial_kernel<<<dim3(N_POINTS / 256, CHUNKS), 256, 0, stream>>>(z, Epk, eev, wd, wi);
    vq_finalize_kernel<<<N_POINTS / 256, 256, 0, stream>>>(z, E, wd, wi, out, partial);
    vq_loss_kernel<<<1, 128, 0, stream>>>(partial, out);
}